// Round 7
// baseline (603.349 us; speedup 1.0000x reference)
//
#include <hip/hip_runtime.h>

#define H 2048
#define HH (H * H)
#define NIDX 2097152
#define BINS 256
#define CH 3

// ---------------- ws layout (R5-proven footprint) ----------------
#define NBUCK 64          // pixel buckets (p>>16): 256KB binpack slice each
#define NLIST 128         // 2 sides x 64
#define CAPG  139264      // per-list capacity: mean 131072, sigma~360
#define WS_HIST_DST 0
#define WS_HIST_REF 3072
#define WS_TABLE    6144
#define WS_ACC      9216
#define WS_DONE_G   9224
#define WS_DONE_L   9228
#define WS_CURS     9728                        // uint[128]
#define WS_CTRL_BYTES 16384                     // zeroed each call
#define WS_SEL      16384                       // uchar[HH] (zeroed by prep)
#define WS_BPS      (16384 + (size_t)HH)        // uint[HH] binpack_src
#define WS_BPR      (WS_BPS + (size_t)HH * 4)   // uint[HH] binpack_ref
#define WS_LIST     (WS_BPR + (size_t)HH * 4)   // ushort[NLIST*CAPG]

__device__ __forceinline__ int bin_of(float v) {
    int b = (int)floorf(v);
    return min(max(b, 0), BINS - 1);
}

// ============================================================
// prep: coalesced pass, packed 3-channel bin words for both sides +
// zero selected. mask==1 -> bin in [127,254] (never 0), so w==0 <=> mask==0.
// High-occupancy streaming kernel: runs at HBM BW (R5-proven).
// ============================================================
__global__ __launch_bounds__(256) void prep_main(
    const float* __restrict__ mask_src, const float* __restrict__ mask_tar,
    const float* __restrict__ refimg, const float* __restrict__ tgtimg,
    unsigned int* __restrict__ bps, unsigned int* __restrict__ bpr,
    unsigned int* __restrict__ sel4)
{
    const int nq = HH / 4;
    const int stride = gridDim.x * 256;
    for (int q = blockIdx.x * 256 + threadIdx.x; q < nq; q += stride) {
        float4 ms4 = ((const float4*)mask_src)[q];
        float4 mt4 = ((const float4*)mask_tar)[q];
        const float ms[4] = { ms4.x, ms4.y, ms4.z, ms4.w };
        const float mt[4] = { mt4.x, mt4.y, mt4.z, mt4.w };
        unsigned int wsrc[4] = { 0u, 0u, 0u, 0u };
        unsigned int wref[4] = { 0u, 0u, 0u, 0u };
        #pragma unroll
        for (int c = 0; c < CH; ++c) {
            float4 r4 = ((const float4*)(refimg + (size_t)c * HH))[q];
            float4 t4 = ((const float4*)(tgtimg + (size_t)c * HH))[q];
            const float rr[4] = { r4.x, r4.y, r4.z, r4.w };
            const float tt[4] = { t4.x, t4.y, t4.z, t4.w };
            #pragma unroll
            for (int e = 0; e < 4; ++e) {
                float vs = (rr[e] * 0.5f + 0.5f) * 255.0f * ms[e];
                float vt = (tt[e] * 0.5f + 0.5f) * 255.0f * mt[e];
                wsrc[e] |= ((unsigned int)bin_of(vs)) << (8 * c);
                wref[e] |= ((unsigned int)bin_of(vt)) << (8 * c);
            }
        }
        uint4 o1 = { wsrc[0], wsrc[1], wsrc[2], wsrc[3] };
        uint4 o2 = { wref[0], wref[1], wref[2], wref[3] };
        ((uint4*)bps)[q] = o1;
        ((uint4*)bpr)[q] = o2;
        sel4[q] = 0u;
    }
}

// ============================================================
// partition: bucket sample positions by p>>16 (R5-proven).
// ============================================================
#define P1_BLOCKS 512
#define P1_SPB (NIDX / P1_BLOCKS)   // 4096 samples/block
#define P1_CAP 128                  // per-list LDS capacity (mean fill 64)

__global__ __launch_bounds__(256) void partition_kernel(
    const int* __restrict__ idx0, const int* __restrict__ idx1,
    const int* __restrict__ idx2, const int* __restrict__ idx3,
    unsigned short* __restrict__ list_g, unsigned int* __restrict__ curs)
{
    __shared__ unsigned short stage[NLIST * P1_CAP];   // 32 KB
    __shared__ unsigned int lcnt[NLIST];
    __shared__ unsigned int lbase[NLIST];
    for (int i = threadIdx.x; i < NLIST; i += 256) lcnt[i] = 0u;
    __syncthreads();

    const int base_k = blockIdx.x * P1_SPB;
    for (int r = 0; r < P1_SPB / 256; ++r) {
        int k = base_k + r * 256 + threadIdx.x;
        int pd = idx0[k] * H + idx1[k];
        int pr = idx2[k] * H + idx3[k];
        {
            int l = pd >> 16;  // 0..63
            unsigned int pos = atomicAdd(&lcnt[l], 1u);
            if (pos < P1_CAP) stage[l * P1_CAP + pos] = (unsigned short)(pd & 0xFFFF);
            else {
                unsigned int g = atomicAdd(&curs[l], 1u);
                if (g < CAPG) list_g[(size_t)l * CAPG + g] = (unsigned short)(pd & 0xFFFF);
            }
        }
        {
            int l = 64 + (pr >> 16);
            unsigned int pos = atomicAdd(&lcnt[l], 1u);
            if (pos < P1_CAP) stage[l * P1_CAP + pos] = (unsigned short)(pr & 0xFFFF);
            else {
                unsigned int g = atomicAdd(&curs[l], 1u);
                if (g < CAPG) list_g[(size_t)l * CAPG + g] = (unsigned short)(pr & 0xFFFF);
            }
        }
    }
    __syncthreads();
    if (threadIdx.x < NLIST) {
        unsigned int n = min(lcnt[threadIdx.x], (unsigned int)P1_CAP);
        lbase[threadIdx.x] = atomicAdd(&curs[threadIdx.x], n);
    }
    __syncthreads();
    for (int b = 0; b < NLIST; ++b) {
        int n = (int)min(lcnt[b], (unsigned int)P1_CAP);
        unsigned int gb = lbase[b];
        for (int e = threadIdx.x; e < n; e += 256) {
            unsigned int gi = gb + e;
            if (gi < CAPG) list_g[(size_t)b * CAPG + gi] = stage[b * P1_CAP + e];
        }
    }
}

// ============================================================
// gather: XCD-localized random reads (R5 structure) with 4-way MLP —
// per iteration each thread issues a dst PAIR + ref PAIR of independent
// L2 loads before consuming any. Last block builds the table (R6-proven).
// ============================================================
__global__ __launch_bounds__(256) void gather_hist_kernel(
    const unsigned short* __restrict__ list_g, const unsigned int* __restrict__ curs,
    const unsigned int* __restrict__ bps, const unsigned int* __restrict__ bpr,
    unsigned char* __restrict__ selected,
    unsigned int* __restrict__ hist_dst, unsigned int* __restrict__ hist_ref,
    int* __restrict__ table, unsigned int* __restrict__ done)
{
    __shared__ unsigned int hd[CH * BINS];
    __shared__ unsigned int hr[CH * BINS];
    __shared__ float wpart[4];
    __shared__ unsigned int is_last;
    const int tid = threadIdx.x;
    for (int i = tid; i < CH * BINS; i += 256) { hd[i] = 0u; hr[i] = 0u; }
    __syncthreads();

    const int xcd = blockIdx.x & 7;
    const int j = blockIdx.x >> 3;   // 0..255 (grid 2048)
    unsigned int zc_d = 0, zc_r = 0;

    for (int phase = 0; phase < 8; ++phase) {
        const int bucket = xcd * 8 + phase;
        const unsigned int pbase = ((unsigned int)bucket) << 16;
        const unsigned short* Ld = list_g + (size_t)bucket * CAPG;
        const unsigned short* Lr = list_g + (size_t)(NBUCK + bucket) * CAPG;
        unsigned int nd = min(curs[bucket], (unsigned int)CAPG);
        unsigned int nr = min(curs[NBUCK + bucket], (unsigned int)CAPG);
        // even chunk covering n with 256 j-blocks
        unsigned int chd = (((nd + 255u) >> 8) + 1u) & ~1u;
        unsigned int chr = (((nr + 255u) >> 8) + 1u) & ~1u;
        unsigned int ed = min(j * chd + chd, nd);
        unsigned int er = min(j * chr + chr, nr);
        unsigned int kd = j * chd + 2 * tid;
        unsigned int kr = j * chr + 2 * tid;

        while (kd < ed || kr < er) {
            int cntd = 0, cntr = 0;
            unsigned int pd0 = 0, pd1 = 0, pr0 = 0, pr1 = 0;
            if (kd < ed) {
                pd0 = pbase | (unsigned int)Ld[kd];
                cntd = 1;
                if (kd + 1 < ed) { pd1 = pbase | (unsigned int)Ld[kd + 1]; cntd = 2; }
            }
            if (kr < er) {
                pr0 = pbase | (unsigned int)Lr[kr];
                cntr = 1;
                if (kr + 1 < er) { pr1 = pbase | (unsigned int)Lr[kr + 1]; cntr = 2; }
            }
            // issue all 4 random loads before consuming anything
            unsigned int wd0 = (cntd > 0) ? bps[pd0] : 0u;
            unsigned int wd1 = (cntd > 1) ? bps[pd1] : 0u;
            unsigned int wr0 = (cntr > 0) ? bpr[pr0] : 0u;
            unsigned int wr1 = (cntr > 1) ? bpr[pr1] : 0u;
            if (cntd > 0) selected[pd0] = 1;
            if (cntd > 1) selected[pd1] = 1;

            if (cntd > 0) {
                if (wd0 == 0u) ++zc_d;
                else {
                    atomicAdd(&hd[0 * BINS + (wd0 & 0xFFu)], 1u);
                    atomicAdd(&hd[1 * BINS + ((wd0 >> 8) & 0xFFu)], 1u);
                    atomicAdd(&hd[2 * BINS + ((wd0 >> 16) & 0xFFu)], 1u);
                }
            }
            if (cntd > 1) {
                if (wd1 == 0u) ++zc_d;
                else {
                    atomicAdd(&hd[0 * BINS + (wd1 & 0xFFu)], 1u);
                    atomicAdd(&hd[1 * BINS + ((wd1 >> 8) & 0xFFu)], 1u);
                    atomicAdd(&hd[2 * BINS + ((wd1 >> 16) & 0xFFu)], 1u);
                }
            }
            if (cntr > 0) {
                if (wr0 == 0u) ++zc_r;
                else {
                    atomicAdd(&hr[0 * BINS + (wr0 & 0xFFu)], 1u);
                    atomicAdd(&hr[1 * BINS + ((wr0 >> 8) & 0xFFu)], 1u);
                    atomicAdd(&hr[2 * BINS + ((wr0 >> 16) & 0xFFu)], 1u);
                }
            }
            if (cntr > 1) {
                if (wr1 == 0u) ++zc_r;
                else {
                    atomicAdd(&hr[0 * BINS + (wr1 & 0xFFu)], 1u);
                    atomicAdd(&hr[1 * BINS + ((wr1 >> 8) & 0xFFu)], 1u);
                    atomicAdd(&hr[2 * BINS + ((wr1 >> 16) & 0xFFu)], 1u);
                }
            }
            kd += 512; kr += 512;
        }
    }

    int zd = (int)zc_d, zr = (int)zc_r;
    #pragma unroll
    for (int off = 32; off; off >>= 1) { zd += __shfl_down(zd, off); zr += __shfl_down(zr, off); }
    if ((tid & 63) == 0) {
        if (zd) {
            atomicAdd(&hd[0 * BINS], (unsigned int)zd);
            atomicAdd(&hd[1 * BINS], (unsigned int)zd);
            atomicAdd(&hd[2 * BINS], (unsigned int)zd);
        }
        if (zr) {
            atomicAdd(&hr[0 * BINS], (unsigned int)zr);
            atomicAdd(&hr[1 * BINS], (unsigned int)zr);
            atomicAdd(&hr[2 * BINS], (unsigned int)zr);
        }
    }
    __syncthreads();
    for (int i = tid; i < CH * BINS; i += 256) {
        unsigned int v = hd[i];
        if (v) atomicAdd(&hist_dst[i], v);
        v = hr[i];
        if (v) atomicAdd(&hist_ref[i], v);
    }

    // -------- last block builds the table --------
    __threadfence();
    __syncthreads();   // ensure all lanes' global atomics issued before counting
    if (tid == 0) is_last = (atomicAdd(done, 1u) == (unsigned int)gridDim.x - 1u) ? 1u : 0u;
    __syncthreads();
    if (is_last) {
        // reuse hd/hr LDS as float scratch (flushed above)
        float* cd = (float*)hd;
        float* cr = (float*)hr;
        const int i = tid, lane = i & 63, wave = i >> 6;
        for (int a = 0; a < 6; ++a) {
            unsigned int* h = (a < 3) ? (hist_dst + a * BINS) : (hist_ref + (a - 3) * BINS);
            float x = (float)atomicAdd(&h[i], 0u);  // coherent device-scope read
            #pragma unroll
            for (int off = 1; off < 64; off <<= 1) {
                float y = __shfl_up(x, off);
                if (lane >= off) x += y;
            }
            if (lane == 63) wpart[wave] = x;
            __syncthreads();
            float prefix = 0.0f;
            #pragma unroll
            for (int w = 0; w < 3; ++w) if (w < wave) prefix += wpart[w];
            x += prefix;
            float tot = wpart[0] + wpart[1] + wpart[2] + wpart[3];
            float* out = (a < 3) ? (cd + a * BINS) : (cr + (a - 3) * BINS);
            __syncthreads();
            out[i] = x / tot;   // exact: integer-valued f32 < 2^24, any add order
            __syncthreads();
        }
        // reference interval search == binary search on non-decreasing cr
        #pragma unroll
        for (int c = 0; c < CH; ++c) {
            int t;
            if (i == 0) t = 0;
            else if (i == BINS - 1) t = BINS - 1;
            else {
                float r = cd[c * BINS + i];
                int lo = 1, hi = BINS - 1;
                while (lo < hi) {
                    int mid = (lo + hi) >> 1;
                    if (cr[c * BINS + mid] < r) lo = mid + 1; else hi = mid;
                }
                t = (cr[c * BINS + lo - 1] <= r) ? lo : i;
            }
            table[c * BINS + i] = t;
        }
    }
}

// ============================================================
// loss + fused finalize (R6-proven done-counter).
// ============================================================
#define LOSS_BLOCKS 2048

__global__ __launch_bounds__(256) void loss_kernel(
    const float* __restrict__ input, const float* __restrict__ refimg,
    const float* __restrict__ mask_src, const unsigned char* __restrict__ selected,
    const int* __restrict__ table, double* __restrict__ acc,
    unsigned int* __restrict__ done, float* __restrict__ out)
{
    __shared__ int tab[CH * BINS];
    for (int i = threadIdx.x; i < CH * BINS; i += 256) tab[i] = table[i];
    __syncthreads();

    float lsum = 0.0f;
    const int nq = HH / 4;
    const int stride = gridDim.x * 256;
    for (int q = blockIdx.x * 256 + threadIdx.x; q < nq; q += stride) {
        float4 m4 = ((const float4*)mask_src)[q];
        uchar4 s4 = ((const uchar4*)selected)[q];
        const unsigned char ss[4] = { s4.x, s4.y, s4.z, s4.w };
        const float mm[4] = { m4.x, m4.y, m4.z, m4.w };
        #pragma unroll
        for (int c = 0; c < CH; ++c) {
            float4 a4 = ((const float4*)(input + (size_t)c * HH))[q];
            float4 r4 = ((const float4*)(refimg + (size_t)c * HH))[q];
            const float aa[4] = { a4.x, a4.y, a4.z, a4.w };
            const float rr[4] = { r4.x, r4.y, r4.z, r4.w };
            #pragma unroll
            for (int e = 0; e < 4; ++e) {
                float m = mm[e];
                float av = (aa[e] * 0.5f + 0.5f) * 255.0f * m;
                float rv = (rr[e] * 0.5f + 0.5f) * 255.0f * m;
                float tv = (float)tab[c * BINS + bin_of(rv)];
                float mv = m * (ss[e] ? tv : rv);
                lsum += fabsf(av - mv);
            }
        }
    }

    double d = (double)lsum;
    #pragma unroll
    for (int off = 32; off; off >>= 1) d += __shfl_down(d, off);
    __shared__ double wsum[4];
    int wid = threadIdx.x >> 6;
    int lane = threadIdx.x & 63;
    if (lane == 0) wsum[wid] = d;
    __syncthreads();
    if (threadIdx.x == 0) {
        double t = wsum[0] + wsum[1] + wsum[2] + wsum[3];
        atomicAdd(acc, t);
        __threadfence();
        unsigned int old = atomicAdd(done, 1u);
        if (old == (unsigned int)gridDim.x - 1u) {
            double tot = atomicAdd(acc, 0.0);  // coherent read
            out[0] = (float)(tot / (double)(CH * (double)HH));
        }
    }
}

// ============================================================

extern "C" void kernel_launch(void* const* d_in, const int* in_sizes, int n_in,
                              void* d_out, int out_size, void* d_ws, size_t ws_size,
                              hipStream_t stream)
{
    const float* input    = (const float*)d_in[0];
    const float* target   = (const float*)d_in[1];
    const float* mask_src = (const float*)d_in[2];
    const float* mask_tar = (const float*)d_in[3];
    const int*   idx0     = (const int*)d_in[4];
    const int*   idx1     = (const int*)d_in[5];
    const int*   idx2     = (const int*)d_in[6];
    const int*   idx3     = (const int*)d_in[7];
    const float* refimg   = (const float*)d_in[8];

    char* ws = (char*)d_ws;
    unsigned int*   hist_dst = (unsigned int*)(ws + WS_HIST_DST);
    unsigned int*   hist_ref = (unsigned int*)(ws + WS_HIST_REF);
    int*            table    = (int*)(ws + WS_TABLE);
    double*         acc      = (double*)(ws + WS_ACC);
    unsigned int*   done_g   = (unsigned int*)(ws + WS_DONE_G);
    unsigned int*   done_l   = (unsigned int*)(ws + WS_DONE_L);
    unsigned int*   curs     = (unsigned int*)(ws + WS_CURS);
    unsigned char*  selected = (unsigned char*)(ws + WS_SEL);
    unsigned int*   bps      = (unsigned int*)(ws + WS_BPS);
    unsigned int*   bpr      = (unsigned int*)(ws + WS_BPR);
    unsigned short* list_g   = (unsigned short*)(ws + WS_LIST);

    hipMemsetAsync(d_ws, 0, WS_CTRL_BYTES, stream);

    prep_main<<<2048, 256, 0, stream>>>(mask_src, mask_tar, refimg, target,
                                        bps, bpr, (unsigned int*)selected);
    partition_kernel<<<P1_BLOCKS, 256, 0, stream>>>(idx0, idx1, idx2, idx3,
                                                    list_g, curs);
    gather_hist_kernel<<<2048, 256, 0, stream>>>(list_g, curs, bps, bpr,
                                                 selected, hist_dst, hist_ref,
                                                 table, done_g);
    loss_kernel<<<LOSS_BLOCKS, 256, 0, stream>>>(input, refimg, mask_src, selected,
                                                 table, acc, done_l, (float*)d_out);
}